// Round 1
// baseline (4622.043 us; speedup 1.0000x reference)
//
#include <hip/hip_runtime.h>

// ---------------------------------------------------------------------------
// DistMultNN (HolE-style scoring) on MI355X.
// out[s] = 3*x^T V x - (Vb)dotx - 0.25*(b^T V b) - x.x,  x = r * circcorr(e1,e2)
// V = inv(W - I) computed on-device: no-pivot register Gauss-Jordan (1 block)
// + 2 Newton-Schulz polish iterations (tiny GEMMs).
// ---------------------------------------------------------------------------

// ============ Kernel 1: augmented Gauss-Jordan inverse, 1 block =============
// 1024 threads; thread (tx=tid>>5, ty=tid&31) owns rows ty*8..+7, cols tx*16..+15
// of the 256x512 augmented [W-I | I]. Column-major wave mapping -> waves whose
// columns are frozen skip the update (active window = 17 of 32 col groups).
__global__ __launch_bounds__(1024) void gj_inv_kernel(const float* __restrict__ W,
                                                      float* __restrict__ V0) {
  const int tid = threadIdx.x;
  const int tx = tid >> 5;   // col group 0..31 (16 cols each, 512 total)
  const int ty = tid & 31;   // row group 0..31 (8 rows each)
  const int r0 = ty << 3;
  const int c0 = tx << 4;

  float g[8][16];
  __shared__ float colbuf[256];
  __shared__ float rowbuf[512];

#pragma unroll
  for (int i = 0; i < 8; ++i) {
    const int r = r0 + i;
#pragma unroll
    for (int j = 0; j < 16; ++j) {
      const int c = c0 + j;
      float v;
      if (c < 256) v = W[r * 256 + c] - ((r == c) ? 1.0f : 0.0f);
      else         v = (r == (c - 256)) ? 1.0f : 0.0f;
      g[i][j] = v;
    }
  }
  __syncthreads();

  for (int k = 0; k < 256; ++k) {
    const int kc = k >> 4, kj = k & 15, kr = k >> 3, ki = k & 7;
    if (tx == kc) {
#pragma unroll
      for (int i = 0; i < 8; ++i) colbuf[r0 + i] = g[i][kj];
    }
    __syncthreads();
    const bool active = (tx >= kc) && (tx <= kc + 16);
    const float pr = 1.0f / colbuf[k];
    if (active && ty == kr) {
#pragma unroll
      for (int j = 0; j < 16; ++j) {
        g[ki][j] *= pr;
        rowbuf[c0 + j] = g[ki][j];
      }
    }
    __syncthreads();
    if (active) {
      float rb[16];
#pragma unroll
      for (int j = 0; j < 16; j += 4) {
        float4 t = *(const float4*)&rowbuf[c0 + j];
        rb[j] = t.x; rb[j + 1] = t.y; rb[j + 2] = t.z; rb[j + 3] = t.w;
      }
#pragma unroll
      for (int i = 0; i < 8; ++i) {
        const int r = r0 + i;
        const float f = (r == k) ? 0.0f : colbuf[r];
#pragma unroll
        for (int j = 0; j < 16; ++j) g[i][j] -= f * rb[j];
      }
    }
    __syncthreads();
  }

  if (tx >= 16) {
#pragma unroll
    for (int i = 0; i < 8; ++i) {
#pragma unroll
      for (int j = 0; j < 16; j += 4) {
        float4 t = make_float4(g[i][j], g[i][j + 1], g[i][j + 2], g[i][j + 3]);
        *(float4*)&V0[(r0 + i) * 256 + (c0 - 256) + j] = t;
      }
    }
  }
}

// ============ Newton-Schulz polish kernels (256^3 f32 GEMMs) ================
// T = (W - I) * Vin.  A-element A[i][k] = W[k*256+i] - (i==k)  (W symmetric).
__global__ __launch_bounds__(64) void ns_mt_kernel(const float* __restrict__ W,
                                                   const float* __restrict__ Vin,
                                                   float* __restrict__ T) {
  const int bi = blockIdx.x >> 3, bj = blockIdx.x & 7;
  const int ti = threadIdx.x >> 3, tj = threadIdx.x & 7;
  const int i0 = bi * 32 + ti * 4, j0 = bj * 32 + tj * 4;
  float acc[4][4] = {};
  for (int k = 0; k < 256; ++k) {
    float4 a4 = *(const float4*)&W[k * 256 + i0];
    float a[4] = {a4.x, a4.y, a4.z, a4.w};
#pragma unroll
    for (int i = 0; i < 4; ++i) a[i] -= ((i0 + i) == k) ? 1.0f : 0.0f;
    float4 b4 = *(const float4*)&Vin[k * 256 + j0];
    const float b[4] = {b4.x, b4.y, b4.z, b4.w};
#pragma unroll
    for (int i = 0; i < 4; ++i)
#pragma unroll
      for (int j = 0; j < 4; ++j) acc[i][j] += a[i] * b[j];
  }
#pragma unroll
  for (int i = 0; i < 4; ++i) {
    float4 t = make_float4(acc[i][0], acc[i][1], acc[i][2], acc[i][3]);
    *(float4*)&T[(i0 + i) * 256 + j0] = t;
  }
}

// Vout = 2*Vin - Vin*T
__global__ __launch_bounds__(64) void ns_upd_kernel(const float* __restrict__ Vin,
                                                    const float* __restrict__ T,
                                                    float* __restrict__ Vout) {
  const int bi = blockIdx.x >> 3, bj = blockIdx.x & 7;
  const int ti = threadIdx.x >> 3, tj = threadIdx.x & 7;
  const int i0 = bi * 32 + ti * 4, j0 = bj * 32 + tj * 4;
  float acc[4][4] = {};
  for (int k = 0; k < 256; ++k) {
    float a[4];
#pragma unroll
    for (int i = 0; i < 4; ++i) a[i] = Vin[(i0 + i) * 256 + k];
    float4 b4 = *(const float4*)&T[k * 256 + j0];
    const float b[4] = {b4.x, b4.y, b4.z, b4.w};
#pragma unroll
    for (int i = 0; i < 4; ++i)
#pragma unroll
      for (int j = 0; j < 4; ++j) acc[i][j] += a[i] * b[j];
  }
#pragma unroll
  for (int i = 0; i < 4; ++i) {
    float4 v = *(const float4*)&Vin[(i0 + i) * 256 + j0];
    float4 t = make_float4(2.0f * v.x - acc[i][0], 2.0f * v.y - acc[i][1],
                           2.0f * v.z - acc[i][2], 2.0f * v.w - acc[i][3]);
    *(float4*)&Vout[(i0 + i) * 256 + j0] = t;
  }
}

// ============ u = V*b, c0 = b.u ==============================================
__global__ __launch_bounds__(256) void compute_u_kernel(const float* __restrict__ V,
                                                        const float* __restrict__ b,
                                                        float* __restrict__ u,
                                                        float* __restrict__ c0) {
  const int tid = threadIdx.x;
  __shared__ float bs[256];
  __shared__ float us[256];
  bs[tid] = b[tid];
  __syncthreads();
  float acc = 0.0f;
  for (int j = 0; j < 256; j += 4) {
    float4 v4 = *(const float4*)&V[tid * 256 + j];
    acc += v4.x * bs[j] + v4.y * bs[j + 1] + v4.z * bs[j + 2] + v4.w * bs[j + 3];
  }
  u[tid] = acc;
  us[tid] = acc * bs[tid];
  __syncthreads();
  if (tid < 64) {
    float s = us[tid] + us[tid + 64] + us[tid + 128] + us[tid + 192];
#pragma unroll
    for (int off = 32; off > 0; off >>= 1) s += __shfl_down(s, off);
    if (tid == 0) c0[0] = s;
  }
}

// ============ Main fused kernel: cc + x + x^T V x + epilogue =================
// 2048 blocks x 256 threads; 32 samples/block (2 cc rounds of 16).
__global__ __launch_bounds__(256) void main_kernel(
    const float* __restrict__ E_ent, const float* __restrict__ E_rel,
    const int* __restrict__ samples, const float* __restrict__ V,
    const float* __restrict__ u, const float* __restrict__ c0p,
    float* __restrict__ out) {
  const int tid = threadIdx.x;
  const int sbase = blockIdx.x * 32;

  __shared__ float e1buf[16][268];   // stride 268: 16B-aligned rows, banks spread
  __shared__ float e2buf[16][268];
  __shared__ float xbuf[256][32];    // x transposed: [k][sample]
  __shared__ float ubuf[256];

  ubuf[tid] = u[tid];

  for (int rnd = 0; rnd < 2; ++rnd) {
    __syncthreads();  // protect e1/e2 reuse across rounds; ubuf visibility
    {  // stage 16 samples' e1,e2 rows (coalesced: 16 lanes span one 1KB row)
      const int ss = tid >> 4;
      const int f0 = (tid & 15) << 4;
      const int sg = sbase + rnd * 16 + ss;
      const int ie1 = samples[sg * 3 + 0];
      const int ie2 = samples[sg * 3 + 2];
      const float* p1 = E_ent + (size_t)ie1 * 256 + f0;
      const float* p2 = E_ent + (size_t)ie2 * 256 + f0;
#pragma unroll
      for (int t = 0; t < 16; t += 4) {
        *(float4*)&e1buf[ss][f0 + t] = *(const float4*)&p1[t];
        *(float4*)&e2buf[ss][f0 + t] = *(const float4*)&p2[t];
      }
    }
    __syncthreads();
    {  // cc: thread (l=tid>>4 -> k-tile of 16, g=tid&15 -> sample)
      const int l = tid >> 4;
      const int g = tid & 15;
      const int k0 = l << 4;
      float acc[16] = {};
      for (int j0 = 0; j0 < 256; j0 += 16) {
        float e1c[16], ea[16], eb[16];
#pragma unroll
        for (int t = 0; t < 16; t += 4) {
          float4 v = *(const float4*)&e1buf[g][j0 + t];
          e1c[t] = v.x; e1c[t + 1] = v.y; e1c[t + 2] = v.z; e1c[t + 3] = v.w;
        }
        const int h0 = (j0 + k0) & 255;
        const int h1 = (h0 + 16) & 255;
#pragma unroll
        for (int t = 0; t < 16; t += 4) {
          float4 va = *(const float4*)&e2buf[g][h0 + t];
          ea[t] = va.x; ea[t + 1] = va.y; ea[t + 2] = va.z; ea[t + 3] = va.w;
          float4 vb = *(const float4*)&e2buf[g][h1 + t];
          eb[t] = vb.x; eb[t + 1] = vb.y; eb[t + 2] = vb.z; eb[t + 3] = vb.w;
        }
#pragma unroll
        for (int jj = 0; jj < 16; ++jj)
#pragma unroll
          for (int m = 0; m < 16; ++m) {
            const int t = jj + m;
            const float w = (t < 16) ? ea[t] : eb[t - 16];
            acc[m] += e1c[jj] * w;
          }
      }
      // x = r * cc -> xbuf (transposed)
      const int sg = sbase + rnd * 16 + g;
      const int ir = samples[sg * 3 + 1];
      const float* rp = E_rel + (size_t)ir * 256 + k0;
#pragma unroll
      for (int m = 0; m < 16; m += 4) {
        float4 r4 = *(const float4*)&rp[m];
        xbuf[k0 + m + 0][rnd * 16 + g] = r4.x * acc[m + 0];
        xbuf[k0 + m + 1][rnd * 16 + g] = r4.y * acc[m + 1];
        xbuf[k0 + m + 2][rnd * 16 + g] = r4.z * acc[m + 2];
        xbuf[k0 + m + 3][rnd * 16 + g] = r4.w * acc[m + 3];
      }
    }
  }
  __syncthreads();

  // GEMM phase: ts=tid>>5 -> 4 samples; tc=tid&31 -> 8 V-columns
  const int ts = tid >> 5, tc = tid & 31;
  const int s0 = ts << 2;
  const int cc0 = tc << 3;
  float z[4][8] = {};
#pragma unroll 4
  for (int l = 0; l < 256; ++l) {
    float4 xv = *(const float4*)&xbuf[l][s0];
    const float xa[4] = {xv.x, xv.y, xv.z, xv.w};
    float4 v0 = *(const float4*)&V[l * 256 + cc0];
    float4 v1 = *(const float4*)&V[l * 256 + cc0 + 4];
    const float vv[8] = {v0.x, v0.y, v0.z, v0.w, v1.x, v1.y, v1.z, v1.w};
#pragma unroll
    for (int i = 0; i < 4; ++i)
#pragma unroll
      for (int j = 0; j < 8; ++j) z[i][j] += xa[i] * vv[j];
  }
  // epilogue: dp = sum_c z*x ; dxx = sum_c x^2 ; dux = sum_c u*x  (per sample)
  float dp[4] = {}, dxx[4] = {}, dux[4] = {};
#pragma unroll
  for (int j = 0; j < 8; ++j) {
    float4 xv = *(const float4*)&xbuf[cc0 + j][s0];
    const float xa[4] = {xv.x, xv.y, xv.z, xv.w};
    const float uu = ubuf[cc0 + j];
#pragma unroll
    for (int i = 0; i < 4; ++i) {
      dp[i]  += z[i][j] * xa[i];
      dxx[i] += xa[i] * xa[i];
      dux[i] += uu * xa[i];
    }
  }
#pragma unroll
  for (int off = 1; off < 32; off <<= 1) {
#pragma unroll
    for (int i = 0; i < 4; ++i) {
      dp[i]  += __shfl_xor(dp[i], off);
      dxx[i] += __shfl_xor(dxx[i], off);
      dux[i] += __shfl_xor(dux[i], off);
    }
  }
  if (tc == 0) {
    const float c0v = c0p[0];
#pragma unroll
    for (int i = 0; i < 4; ++i) {
      out[sbase + s0 + i] = 3.0f * dp[i] - dux[i] - 0.25f * c0v - dxx[i];
    }
  }
}

// ============================ launcher ======================================
extern "C" void kernel_launch(void* const* d_in, const int* in_sizes, int n_in,
                              void* d_out, int out_size, void* d_ws, size_t ws_size,
                              hipStream_t stream) {
  const float* E_ent   = (const float*)d_in[0];
  const float* E_rel   = (const float*)d_in[1];
  const float* W       = (const float*)d_in[2];
  const float* b       = (const float*)d_in[3];
  const int*   samples = (const int*)d_in[4];
  float* out = (float*)d_out;
  float* ws  = (float*)d_ws;

  float* VA = ws;            // 65536 f32 (V0 -> final V)
  float* VB = ws + 65536;    // T scratch
  float* VC = ws + 131072;   // V1
  float* ub = ws + 196608;   // 256
  float* c0 = ws + 196864;   // 1

  gj_inv_kernel<<<1, 1024, 0, stream>>>(W, VA);
  // Newton-Schulz polish x2: V <- V(2I - (W-I)V)
  ns_mt_kernel<<<64, 64, 0, stream>>>(W, VA, VB);
  ns_upd_kernel<<<64, 64, 0, stream>>>(VA, VB, VC);
  ns_mt_kernel<<<64, 64, 0, stream>>>(W, VC, VB);
  ns_upd_kernel<<<64, 64, 0, stream>>>(VC, VB, VA);
  compute_u_kernel<<<1, 256, 0, stream>>>(VA, b, ub, c0);

  main_kernel<<<65536 / 32, 256, 0, stream>>>(E_ent, E_rel, samples, VA, ub, c0, out);
}

// Round 2
// 762.565 us; speedup vs baseline: 6.0612x; 6.0612x over previous
//
#include <hip/hip_runtime.h>

// ---------------------------------------------------------------------------
// DistMultNN (HolE-style scoring) on MI355X.
// out[s] = 3*x^T V x - (Vb).x - 0.25*(b^T V b) - x.x,  x = r * circcorr(e1,e2)
// V = inv(W - I) computed on-device: in-place no-pivot register Gauss-Jordan
// (1 block, all register indices compile-time) + 2 Newton-Schulz polish iters.
// ---------------------------------------------------------------------------

// ============ Kernel 1: in-place Gauss-Jordan inverse, 1 block ==============
// 1024 threads; thread (ty=tid>>5, tx=tid&31) owns rows ty*8..+7, cols tx*8..+7
// of the 256x256 matrix (64 regs/thread). Pivot index kj is COMPILE-TIME via
// 8x inner unroll (k = kg*8+kj, so k&7 == kj) -> no scratch spill (rule #20).
// In-place GJ: A[k][j]/=p; A[i][j]-=A[i][k]*A[k][j]/p; A[i][k]=-A[i][k]/p;
// A[k][k]=1/p. Column-k update made uniform via rowbuf[k]=1+1/p trick.
__global__ __launch_bounds__(1024) void gj_inv_kernel(const float* __restrict__ W,
                                                      float* __restrict__ V0) {
  const int tid = threadIdx.x;
  const int tx = tid & 31;   // col group: cols tx*8..+7
  const int ty = tid >> 5;   // row group: rows ty*8..+7
  const int r0 = ty << 3;
  const int c0 = tx << 3;

  float g[8][8];
  __shared__ float colbuf[256];
  __shared__ float rowbuf[256];

  // load A = W - I
#pragma unroll
  for (int i = 0; i < 8; ++i) {
#pragma unroll
    for (int j = 0; j < 8; j += 4) {
      float4 w4 = *(const float4*)&W[(r0 + i) * 256 + c0 + j];
      g[i][j] = w4.x; g[i][j + 1] = w4.y; g[i][j + 2] = w4.z; g[i][j + 3] = w4.w;
    }
#pragma unroll
    for (int j = 0; j < 8; ++j)
      if ((r0 + i) == (c0 + j)) g[i][j] -= 1.0f;
  }
  __syncthreads();

  for (int kg = 0; kg < 32; ++kg) {
#pragma unroll
    for (int kj = 0; kj < 8; ++kj) {
      const int k = kg * 8 + kj;
      // phase 1: threads owning column k publish it (pre-update values)
      if (tx == kg) {
#pragma unroll
        for (int i = 0; i < 8; ++i) colbuf[r0 + i] = g[i][kj];
      }
      __syncthreads();
      const float pr = 1.0f / colbuf[k];
      // phase 2: pivot-row threads scale the row, publish scaled row.
      // rowbuf[k] = 1+pr so the phase-3 FMA also produces A[i][k] = -f*pr.
      if (ty == kg) {
#pragma unroll
        for (int j = 0; j < 8; ++j) {
          const bool isp = (tx == kg) && (j == kj);  // this is element (k,k)
          const float nv = isp ? pr : g[kj][j] * pr;
          g[kj][j] = nv;
          rowbuf[c0 + j] = isp ? (1.0f + pr) : nv;
        }
      }
      __syncthreads();
      // phase 3: uniform rank-1 elimination (pivot row masked via f=0)
      float rb[8];
#pragma unroll
      for (int j = 0; j < 8; j += 4) {
        float4 t = *(const float4*)&rowbuf[c0 + j];
        rb[j] = t.x; rb[j + 1] = t.y; rb[j + 2] = t.z; rb[j + 3] = t.w;
      }
#pragma unroll
      for (int i = 0; i < 8; ++i) {
        float f = colbuf[r0 + i];
        f = ((r0 + i) == k) ? 0.0f : f;
#pragma unroll
        for (int j = 0; j < 8; ++j) g[i][j] = fmaf(-f, rb[j], g[i][j]);
      }
      __syncthreads();
    }
  }

  // write V0 (thread writes 8 rows x 8 cols; lanes cover contiguous 32B cols)
#pragma unroll
  for (int i = 0; i < 8; ++i) {
#pragma unroll
    for (int j = 0; j < 8; j += 4) {
      *(float4*)&V0[(r0 + i) * 256 + c0 + j] =
          make_float4(g[i][j], g[i][j + 1], g[i][j + 2], g[i][j + 3]);
    }
  }
}

// ============ Newton-Schulz polish kernels (256^3 f32 GEMMs) ================
// T = (W - I) * Vin.  A-element A[i][k] = W[k*256+i] - (i==k)  (W symmetric).
__global__ __launch_bounds__(64) void ns_mt_kernel(const float* __restrict__ W,
                                                   const float* __restrict__ Vin,
                                                   float* __restrict__ T) {
  const int bi = blockIdx.x >> 3, bj = blockIdx.x & 7;
  const int ti = threadIdx.x >> 3, tj = threadIdx.x & 7;
  const int i0 = bi * 32 + ti * 4, j0 = bj * 32 + tj * 4;
  float acc[4][4] = {};
  for (int k = 0; k < 256; ++k) {
    float4 a4 = *(const float4*)&W[k * 256 + i0];
    float a[4] = {a4.x, a4.y, a4.z, a4.w};
#pragma unroll
    for (int i = 0; i < 4; ++i) a[i] -= ((i0 + i) == k) ? 1.0f : 0.0f;
    float4 b4 = *(const float4*)&Vin[k * 256 + j0];
    const float b[4] = {b4.x, b4.y, b4.z, b4.w};
#pragma unroll
    for (int i = 0; i < 4; ++i)
#pragma unroll
      for (int j = 0; j < 4; ++j) acc[i][j] += a[i] * b[j];
  }
#pragma unroll
  for (int i = 0; i < 4; ++i) {
    float4 t = make_float4(acc[i][0], acc[i][1], acc[i][2], acc[i][3]);
    *(float4*)&T[(i0 + i) * 256 + j0] = t;
  }
}

// Vout = 2*Vin - Vin*T
__global__ __launch_bounds__(64) void ns_upd_kernel(const float* __restrict__ Vin,
                                                    const float* __restrict__ T,
                                                    float* __restrict__ Vout) {
  const int bi = blockIdx.x >> 3, bj = blockIdx.x & 7;
  const int ti = threadIdx.x >> 3, tj = threadIdx.x & 7;
  const int i0 = bi * 32 + ti * 4, j0 = bj * 32 + tj * 4;
  float acc[4][4] = {};
  for (int k = 0; k < 256; ++k) {
    float a[4];
#pragma unroll
    for (int i = 0; i < 4; ++i) a[i] = Vin[(i0 + i) * 256 + k];
    float4 b4 = *(const float4*)&T[k * 256 + j0];
    const float b[4] = {b4.x, b4.y, b4.z, b4.w};
#pragma unroll
    for (int i = 0; i < 4; ++i)
#pragma unroll
      for (int j = 0; j < 4; ++j) acc[i][j] += a[i] * b[j];
  }
#pragma unroll
  for (int i = 0; i < 4; ++i) {
    float4 v = *(const float4*)&Vin[(i0 + i) * 256 + j0];
    float4 t = make_float4(2.0f * v.x - acc[i][0], 2.0f * v.y - acc[i][1],
                           2.0f * v.z - acc[i][2], 2.0f * v.w - acc[i][3]);
    *(float4*)&Vout[(i0 + i) * 256 + j0] = t;
  }
}

// ============ u = V*b, c0 = b.u ==============================================
__global__ __launch_bounds__(256) void compute_u_kernel(const float* __restrict__ V,
                                                        const float* __restrict__ b,
                                                        float* __restrict__ u,
                                                        float* __restrict__ c0) {
  const int tid = threadIdx.x;
  __shared__ float bs[256];
  __shared__ float us[256];
  bs[tid] = b[tid];
  __syncthreads();
  float acc = 0.0f;
  for (int j = 0; j < 256; j += 4) {
    float4 v4 = *(const float4*)&V[tid * 256 + j];
    acc += v4.x * bs[j] + v4.y * bs[j + 1] + v4.z * bs[j + 2] + v4.w * bs[j + 3];
  }
  u[tid] = acc;
  us[tid] = acc * bs[tid];
  __syncthreads();
  if (tid < 64) {
    float s = us[tid] + us[tid + 64] + us[tid + 128] + us[tid + 192];
#pragma unroll
    for (int off = 32; off > 0; off >>= 1) s += __shfl_down(s, off);
    if (tid == 0) c0[0] = s;
  }
}

// ============ Main fused kernel: cc + x + x^T V x + epilogue =================
// 2048 blocks x 256 threads; 32 samples/block (2 cc rounds of 16).
__global__ __launch_bounds__(256) void main_kernel(
    const float* __restrict__ E_ent, const float* __restrict__ E_rel,
    const int* __restrict__ samples, const float* __restrict__ V,
    const float* __restrict__ u, const float* __restrict__ c0p,
    float* __restrict__ out) {
  const int tid = threadIdx.x;
  const int sbase = blockIdx.x * 32;

  __shared__ float e1buf[16][268];   // stride 268: 16B-aligned rows, banks spread
  __shared__ float e2buf[16][268];
  __shared__ float xbuf[256][32];    // x transposed: [k][sample]
  __shared__ float ubuf[256];

  ubuf[tid] = u[tid];

  for (int rnd = 0; rnd < 2; ++rnd) {
    __syncthreads();  // protect e1/e2 reuse across rounds; ubuf visibility
    {  // stage 16 samples' e1,e2 rows (coalesced: 16 lanes span one 1KB row)
      const int ss = tid >> 4;
      const int f0 = (tid & 15) << 4;
      const int sg = sbase + rnd * 16 + ss;
      const int ie1 = samples[sg * 3 + 0];
      const int ie2 = samples[sg * 3 + 2];
      const float* p1 = E_ent + (size_t)ie1 * 256 + f0;
      const float* p2 = E_ent + (size_t)ie2 * 256 + f0;
#pragma unroll
      for (int t = 0; t < 16; t += 4) {
        *(float4*)&e1buf[ss][f0 + t] = *(const float4*)&p1[t];
        *(float4*)&e2buf[ss][f0 + t] = *(const float4*)&p2[t];
      }
    }
    __syncthreads();
    {  // cc: thread (l=tid>>4 -> k-tile of 16, g=tid&15 -> sample)
      const int l = tid >> 4;
      const int g = tid & 15;
      const int k0 = l << 4;
      float acc[16] = {};
      for (int j0 = 0; j0 < 256; j0 += 16) {
        float e1c[16], ea[16], eb[16];
#pragma unroll
        for (int t = 0; t < 16; t += 4) {
          float4 v = *(const float4*)&e1buf[g][j0 + t];
          e1c[t] = v.x; e1c[t + 1] = v.y; e1c[t + 2] = v.z; e1c[t + 3] = v.w;
        }
        const int h0 = (j0 + k0) & 255;
        const int h1 = (h0 + 16) & 255;
#pragma unroll
        for (int t = 0; t < 16; t += 4) {
          float4 va = *(const float4*)&e2buf[g][h0 + t];
          ea[t] = va.x; ea[t + 1] = va.y; ea[t + 2] = va.z; ea[t + 3] = va.w;
          float4 vb = *(const float4*)&e2buf[g][h1 + t];
          eb[t] = vb.x; eb[t + 1] = vb.y; eb[t + 2] = vb.z; eb[t + 3] = vb.w;
        }
#pragma unroll
        for (int jj = 0; jj < 16; ++jj)
#pragma unroll
          for (int m = 0; m < 16; ++m) {
            const int t = jj + m;
            const float w = (t < 16) ? ea[t] : eb[t - 16];
            acc[m] += e1c[jj] * w;
          }
      }
      // x = r * cc -> xbuf (transposed)
      const int sg = sbase + rnd * 16 + g;
      const int ir = samples[sg * 3 + 1];
      const float* rp = E_rel + (size_t)ir * 256 + k0;
#pragma unroll
      for (int m = 0; m < 16; m += 4) {
        float4 r4 = *(const float4*)&rp[m];
        xbuf[k0 + m + 0][rnd * 16 + g] = r4.x * acc[m + 0];
        xbuf[k0 + m + 1][rnd * 16 + g] = r4.y * acc[m + 1];
        xbuf[k0 + m + 2][rnd * 16 + g] = r4.z * acc[m + 2];
        xbuf[k0 + m + 3][rnd * 16 + g] = r4.w * acc[m + 3];
      }
    }
  }
  __syncthreads();

  // GEMM phase: ts=tid>>5 -> 4 samples; tc=tid&31 -> 8 V-columns
  const int ts = tid >> 5, tc = tid & 31;
  const int s0 = ts << 2;
  const int cc0 = tc << 3;
  float z[4][8] = {};
#pragma unroll 4
  for (int l = 0; l < 256; ++l) {
    float4 xv = *(const float4*)&xbuf[l][s0];
    const float xa[4] = {xv.x, xv.y, xv.z, xv.w};
    float4 v0 = *(const float4*)&V[l * 256 + cc0];
    float4 v1 = *(const float4*)&V[l * 256 + cc0 + 4];
    const float vv[8] = {v0.x, v0.y, v0.z, v0.w, v1.x, v1.y, v1.z, v1.w};
#pragma unroll
    for (int i = 0; i < 4; ++i)
#pragma unroll
      for (int j = 0; j < 8; ++j) z[i][j] += xa[i] * vv[j];
  }
  // epilogue: dp = sum_c z*x ; dxx = sum_c x^2 ; dux = sum_c u*x  (per sample)
  float dp[4] = {}, dxx[4] = {}, dux[4] = {};
#pragma unroll
  for (int j = 0; j < 8; ++j) {
    float4 xv = *(const float4*)&xbuf[cc0 + j][s0];
    const float xa[4] = {xv.x, xv.y, xv.z, xv.w};
    const float uu = ubuf[cc0 + j];
#pragma unroll
    for (int i = 0; i < 4; ++i) {
      dp[i]  += z[i][j] * xa[i];
      dxx[i] += xa[i] * xa[i];
      dux[i] += uu * xa[i];
    }
  }
#pragma unroll
  for (int off = 1; off < 32; off <<= 1) {
#pragma unroll
    for (int i = 0; i < 4; ++i) {
      dp[i]  += __shfl_xor(dp[i], off);
      dxx[i] += __shfl_xor(dxx[i], off);
      dux[i] += __shfl_xor(dux[i], off);
    }
  }
  if (tc == 0) {
    const float c0v = c0p[0];
#pragma unroll
    for (int i = 0; i < 4; ++i) {
      out[sbase + s0 + i] = 3.0f * dp[i] - dux[i] - 0.25f * c0v - dxx[i];
    }
  }
}

// ============================ launcher ======================================
extern "C" void kernel_launch(void* const* d_in, const int* in_sizes, int n_in,
                              void* d_out, int out_size, void* d_ws, size_t ws_size,
                              hipStream_t stream) {
  const float* E_ent   = (const float*)d_in[0];
  const float* E_rel   = (const float*)d_in[1];
  const float* W       = (const float*)d_in[2];
  const float* b       = (const float*)d_in[3];
  const int*   samples = (const int*)d_in[4];
  float* out = (float*)d_out;
  float* ws  = (float*)d_ws;

  float* VA = ws;            // 65536 f32 (V0 -> final V)
  float* VB = ws + 65536;    // T scratch
  float* VC = ws + 131072;   // V1
  float* ub = ws + 196608;   // 256
  float* c0 = ws + 196864;   // 1

  gj_inv_kernel<<<1, 1024, 0, stream>>>(W, VA);
  // Newton-Schulz polish x2: V <- V(2I - (W-I)V)
  ns_mt_kernel<<<64, 64, 0, stream>>>(W, VA, VB);
  ns_upd_kernel<<<64, 64, 0, stream>>>(VA, VB, VC);
  ns_mt_kernel<<<64, 64, 0, stream>>>(W, VC, VB);
  ns_upd_kernel<<<64, 64, 0, stream>>>(VC, VB, VA);
  compute_u_kernel<<<1, 256, 0, stream>>>(VA, b, ub, c0);

  main_kernel<<<65536 / 32, 256, 0, stream>>>(E_ent, E_rel, samples, VA, ub, c0, out);
}

// Round 3
// 685.841 us; speedup vs baseline: 6.7392x; 1.1119x over previous
//
#include <hip/hip_runtime.h>

// ---------------------------------------------------------------------------
// DistMultNN (HolE-style scoring) on MI355X.
// out[s] = 3*x^T V x - (Vb).x - 0.25*(b^T V b) - x.x,  x = r * circcorr(e1,e2)
// V = inv(W - I): 1-block BLOCKED Gauss-Jordan (8-wide panels, 32 macro steps,
// 2 barriers each; panel factored in-register by one half-wave via __shfl)
// + 2 Newton-Schulz polish iterations. All register indices compile-time.
// ---------------------------------------------------------------------------

// ============ Kernel 1: blocked in-place Gauss-Jordan inverse, 1 block ======
// 1024 threads; thread (ty=tid>>5, tx=tid&31) owns rows ty*8..+7, cols tx*8..+7
// (g[8][8] = 64 VGPRs; launch_bounds(1024,4) allows 128 -> no spill).
// Macro step kg (pivot cols K=kg*8..+7):
//   phase A: pivot row-block threads (ty==kg; lanes (kg&1)*32.. of wave kg>>1)
//            run 8 scalar GJ steps on their 8x256 panel in registers (shfl
//            broadcasts), leaving [Pinv | Pinv*Arest]; publish rowbuf with +I
//            on K cols (block analog of the 1+pr trick). Meanwhile col-owners
//            (tx==kg, ty!=kg) publish pre-update column block to colbuf.
//   phase B: all ty!=kg threads: rank-8 update g -= C*R (uniform; K-col result
//            -C*Pinv falls out of the +I trick). Pivot rows skip (final).
__global__ __launch_bounds__(1024, 4) void gj_inv_kernel(const float* __restrict__ W,
                                                         float* __restrict__ V0) {
  const int tid = threadIdx.x;
  const int tx = tid & 31;   // col group: cols tx*8..+7
  const int ty = tid >> 5;   // row group: rows ty*8..+7
  const int r0 = ty << 3;
  const int c0 = tx << 3;

  float g[8][8];
  __shared__ float colbuf[256][8];   // [row][m]: column block K, pre-update
  __shared__ float rowbuf[8][264];   // [m][col]: scaled pivot rows (+I on K)

  // load A = W - I
#pragma unroll
  for (int i = 0; i < 8; ++i) {
#pragma unroll
    for (int j = 0; j < 8; j += 4) {
      float4 w4 = *(const float4*)&W[(r0 + i) * 256 + c0 + j];
      g[i][j] = w4.x; g[i][j + 1] = w4.y; g[i][j + 2] = w4.z; g[i][j + 3] = w4.w;
    }
#pragma unroll
    for (int j = 0; j < 8; ++j)
      if ((r0 + i) == (c0 + j)) g[i][j] -= 1.0f;
  }
  __syncthreads();

  for (int kg = 0; kg < 32; ++kg) {
    if (ty == kg) {
      // ---- phase A: in-register panel GJ over the 8x256 pivot row-block ----
      const int L0 = (kg & 1) << 5;  // active half-wave base lane
#pragma unroll
      for (int kj = 0; kj < 8; ++kj) {
        float c[8];
#pragma unroll
        for (int i = 0; i < 8; ++i) c[i] = __shfl(g[i][kj], L0 + kg, 64);
        const float pr = 1.0f / c[kj];
        // scale pivot row; pivot element becomes pr
#pragma unroll
        for (int j = 0; j < 8; ++j) g[kj][j] *= pr;
        if (tx == kg) g[kj][kj] = pr;
        // eliminate other panel rows; K-col entries -> -c[i]*pr
#pragma unroll
        for (int i = 0; i < 8; ++i) {
          if (i == kj) continue;
#pragma unroll
          for (int j = 0; j < 8; ++j) g[i][j] = fmaf(-c[i], g[kj][j], g[i][j]);
          if (tx == kg) g[i][kj] = -c[i] * pr;
        }
      }
      // publish scaled rows; +I on the K-column tile (tx==kg)
#pragma unroll
      for (int m = 0; m < 8; ++m) {
        float r4[8];
#pragma unroll
        for (int j = 0; j < 8; ++j)
          r4[j] = g[m][j] + ((tx == kg && j == m) ? 1.0f : 0.0f);
        *(float4*)&rowbuf[m][c0]     = make_float4(r4[0], r4[1], r4[2], r4[3]);
        *(float4*)&rowbuf[m][c0 + 4] = make_float4(r4[4], r4[5], r4[6], r4[7]);
      }
    } else if (tx == kg) {
      // ---- phase A': publish pre-update column block ----
#pragma unroll
      for (int i = 0; i < 8; ++i) {
        *(float4*)&colbuf[r0 + i][0] = make_float4(g[i][0], g[i][1], g[i][2], g[i][3]);
        *(float4*)&colbuf[r0 + i][4] = make_float4(g[i][4], g[i][5], g[i][6], g[i][7]);
      }
    }
    __syncthreads();
    if (ty != kg) {
      // ---- phase B: rank-8 update g -= C * R ----
#pragma unroll
      for (int m = 0; m < 8; ++m) {
        float rm[8];
        {
          float4 t0 = *(const float4*)&rowbuf[m][c0];
          float4 t1 = *(const float4*)&rowbuf[m][c0 + 4];
          rm[0] = t0.x; rm[1] = t0.y; rm[2] = t0.z; rm[3] = t0.w;
          rm[4] = t1.x; rm[5] = t1.y; rm[6] = t1.z; rm[7] = t1.w;
        }
#pragma unroll
        for (int i = 0; i < 8; ++i) {
          const float f = colbuf[r0 + i][m];   // 32-lane broadcast read
#pragma unroll
          for (int j = 0; j < 8; ++j) g[i][j] = fmaf(-f, rm[j], g[i][j]);
        }
      }
    }
    __syncthreads();
  }

  // write V (in-place result is the inverse)
#pragma unroll
  for (int i = 0; i < 8; ++i) {
#pragma unroll
    for (int j = 0; j < 8; j += 4) {
      *(float4*)&V0[(r0 + i) * 256 + c0 + j] =
          make_float4(g[i][j], g[i][j + 1], g[i][j + 2], g[i][j + 3]);
    }
  }
}

// ============ Newton-Schulz polish kernels (256^3 f32 GEMMs) ================
// T = (W - I) * Vin.  A-element A[i][k] = W[k*256+i] - (i==k)  (W symmetric).
__global__ __launch_bounds__(64) void ns_mt_kernel(const float* __restrict__ W,
                                                   const float* __restrict__ Vin,
                                                   float* __restrict__ T) {
  const int bi = blockIdx.x >> 3, bj = blockIdx.x & 7;
  const int ti = threadIdx.x >> 3, tj = threadIdx.x & 7;
  const int i0 = bi * 32 + ti * 4, j0 = bj * 32 + tj * 4;
  float acc[4][4] = {};
  for (int k = 0; k < 256; ++k) {
    float4 a4 = *(const float4*)&W[k * 256 + i0];
    float a[4] = {a4.x, a4.y, a4.z, a4.w};
#pragma unroll
    for (int i = 0; i < 4; ++i) a[i] -= ((i0 + i) == k) ? 1.0f : 0.0f;
    float4 b4 = *(const float4*)&Vin[k * 256 + j0];
    const float b[4] = {b4.x, b4.y, b4.z, b4.w};
#pragma unroll
    for (int i = 0; i < 4; ++i)
#pragma unroll
      for (int j = 0; j < 4; ++j) acc[i][j] += a[i] * b[j];
  }
#pragma unroll
  for (int i = 0; i < 4; ++i) {
    float4 t = make_float4(acc[i][0], acc[i][1], acc[i][2], acc[i][3]);
    *(float4*)&T[(i0 + i) * 256 + j0] = t;
  }
}

// Vout = 2*Vin - Vin*T
__global__ __launch_bounds__(64) void ns_upd_kernel(const float* __restrict__ Vin,
                                                    const float* __restrict__ T,
                                                    float* __restrict__ Vout) {
  const int bi = blockIdx.x >> 3, bj = blockIdx.x & 7;
  const int ti = threadIdx.x >> 3, tj = threadIdx.x & 7;
  const int i0 = bi * 32 + ti * 4, j0 = bj * 32 + tj * 4;
  float acc[4][4] = {};
  for (int k = 0; k < 256; ++k) {
    float a[4];
#pragma unroll
    for (int i = 0; i < 4; ++i) a[i] = Vin[(i0 + i) * 256 + k];
    float4 b4 = *(const float4*)&T[k * 256 + j0];
    const float b[4] = {b4.x, b4.y, b4.z, b4.w};
#pragma unroll
    for (int i = 0; i < 4; ++i)
#pragma unroll
      for (int j = 0; j < 4; ++j) acc[i][j] += a[i] * b[j];
  }
#pragma unroll
  for (int i = 0; i < 4; ++i) {
    float4 v = *(const float4*)&Vin[(i0 + i) * 256 + j0];
    float4 t = make_float4(2.0f * v.x - acc[i][0], 2.0f * v.y - acc[i][1],
                           2.0f * v.z - acc[i][2], 2.0f * v.w - acc[i][3]);
    *(float4*)&Vout[(i0 + i) * 256 + j0] = t;
  }
}

// ============ u = V*b, c0 = b.u ==============================================
__global__ __launch_bounds__(256) void compute_u_kernel(const float* __restrict__ V,
                                                        const float* __restrict__ b,
                                                        float* __restrict__ u,
                                                        float* __restrict__ c0) {
  const int tid = threadIdx.x;
  __shared__ float bs[256];
  __shared__ float us[256];
  bs[tid] = b[tid];
  __syncthreads();
  float acc = 0.0f;
  for (int j = 0; j < 256; j += 4) {
    float4 v4 = *(const float4*)&V[tid * 256 + j];
    acc += v4.x * bs[j] + v4.y * bs[j + 1] + v4.z * bs[j + 2] + v4.w * bs[j + 3];
  }
  u[tid] = acc;
  us[tid] = acc * bs[tid];
  __syncthreads();
  if (tid < 64) {
    float s = us[tid] + us[tid + 64] + us[tid + 128] + us[tid + 192];
#pragma unroll
    for (int off = 32; off > 0; off >>= 1) s += __shfl_down(s, off);
    if (tid == 0) c0[0] = s;
  }
}

// ============ Main fused kernel: cc + x + x^T V x + epilogue =================
// 2048 blocks x 256 threads; 32 samples/block (2 cc rounds of 16).
__global__ __launch_bounds__(256) void main_kernel(
    const float* __restrict__ E_ent, const float* __restrict__ E_rel,
    const int* __restrict__ samples, const float* __restrict__ V,
    const float* __restrict__ u, const float* __restrict__ c0p,
    float* __restrict__ out) {
  const int tid = threadIdx.x;
  const int sbase = blockIdx.x * 32;

  __shared__ float e1buf[16][268];   // stride 268: 16B-aligned rows, banks spread
  __shared__ float e2buf[16][268];
  __shared__ float xbuf[256][32];    // x transposed: [k][sample]
  __shared__ float ubuf[256];

  ubuf[tid] = u[tid];

  for (int rnd = 0; rnd < 2; ++rnd) {
    __syncthreads();  // protect e1/e2 reuse across rounds; ubuf visibility
    {  // stage 16 samples' e1,e2 rows (coalesced: 16 lanes span one 1KB row)
      const int ss = tid >> 4;
      const int f0 = (tid & 15) << 4;
      const int sg = sbase + rnd * 16 + ss;
      const int ie1 = samples[sg * 3 + 0];
      const int ie2 = samples[sg * 3 + 2];
      const float* p1 = E_ent + (size_t)ie1 * 256 + f0;
      const float* p2 = E_ent + (size_t)ie2 * 256 + f0;
#pragma unroll
      for (int t = 0; t < 16; t += 4) {
        *(float4*)&e1buf[ss][f0 + t] = *(const float4*)&p1[t];
        *(float4*)&e2buf[ss][f0 + t] = *(const float4*)&p2[t];
      }
    }
    __syncthreads();
    {  // cc: thread (l=tid>>4 -> k-tile of 16, g=tid&15 -> sample)
      const int l = tid >> 4;
      const int g = tid & 15;
      const int k0 = l << 4;
      float acc[16] = {};
      for (int j0 = 0; j0 < 256; j0 += 16) {
        float e1c[16], ea[16], eb[16];
#pragma unroll
        for (int t = 0; t < 16; t += 4) {
          float4 v = *(const float4*)&e1buf[g][j0 + t];
          e1c[t] = v.x; e1c[t + 1] = v.y; e1c[t + 2] = v.z; e1c[t + 3] = v.w;
        }
        const int h0 = (j0 + k0) & 255;
        const int h1 = (h0 + 16) & 255;
#pragma unroll
        for (int t = 0; t < 16; t += 4) {
          float4 va = *(const float4*)&e2buf[g][h0 + t];
          ea[t] = va.x; ea[t + 1] = va.y; ea[t + 2] = va.z; ea[t + 3] = va.w;
          float4 vb = *(const float4*)&e2buf[g][h1 + t];
          eb[t] = vb.x; eb[t + 1] = vb.y; eb[t + 2] = vb.z; eb[t + 3] = vb.w;
        }
#pragma unroll
        for (int jj = 0; jj < 16; ++jj)
#pragma unroll
          for (int m = 0; m < 16; ++m) {
            const int t = jj + m;
            const float w = (t < 16) ? ea[t] : eb[t - 16];
            acc[m] += e1c[jj] * w;
          }
      }
      // x = r * cc -> xbuf (transposed)
      const int sg = sbase + rnd * 16 + g;
      const int ir = samples[sg * 3 + 1];
      const float* rp = E_rel + (size_t)ir * 256 + k0;
#pragma unroll
      for (int m = 0; m < 16; m += 4) {
        float4 r4 = *(const float4*)&rp[m];
        xbuf[k0 + m + 0][rnd * 16 + g] = r4.x * acc[m + 0];
        xbuf[k0 + m + 1][rnd * 16 + g] = r4.y * acc[m + 1];
        xbuf[k0 + m + 2][rnd * 16 + g] = r4.z * acc[m + 2];
        xbuf[k0 + m + 3][rnd * 16 + g] = r4.w * acc[m + 3];
      }
    }
  }
  __syncthreads();

  // GEMM phase: ts=tid>>5 -> 4 samples; tc=tid&31 -> 8 V-columns
  const int ts = tid >> 5, tc = tid & 31;
  const int s0 = ts << 2;
  const int cc0 = tc << 3;
  float z[4][8] = {};
#pragma unroll 4
  for (int l = 0; l < 256; ++l) {
    float4 xv = *(const float4*)&xbuf[l][s0];
    const float xa[4] = {xv.x, xv.y, xv.z, xv.w};
    float4 v0 = *(const float4*)&V[l * 256 + cc0];
    float4 v1 = *(const float4*)&V[l * 256 + cc0 + 4];
    const float vv[8] = {v0.x, v0.y, v0.z, v0.w, v1.x, v1.y, v1.z, v1.w};
#pragma unroll
    for (int i = 0; i < 4; ++i)
#pragma unroll
      for (int j = 0; j < 8; ++j) z[i][j] += xa[i] * vv[j];
  }
  // epilogue: dp = sum_c z*x ; dxx = sum_c x^2 ; dux = sum_c u*x  (per sample)
  float dp[4] = {}, dxx[4] = {}, dux[4] = {};
#pragma unroll
  for (int j = 0; j < 8; ++j) {
    float4 xv = *(const float4*)&xbuf[cc0 + j][s0];
    const float xa[4] = {xv.x, xv.y, xv.z, xv.w};
    const float uu = ubuf[cc0 + j];
#pragma unroll
    for (int i = 0; i < 4; ++i) {
      dp[i]  += z[i][j] * xa[i];
      dxx[i] += xa[i] * xa[i];
      dux[i] += uu * xa[i];
    }
  }
#pragma unroll
  for (int off = 1; off < 32; off <<= 1) {
#pragma unroll
    for (int i = 0; i < 4; ++i) {
      dp[i]  += __shfl_xor(dp[i], off);
      dxx[i] += __shfl_xor(dxx[i], off);
      dux[i] += __shfl_xor(dux[i], off);
    }
  }
  if (tc == 0) {
    const float c0v = c0p[0];
#pragma unroll
    for (int i = 0; i < 4; ++i) {
      out[sbase + s0 + i] = 3.0f * dp[i] - dux[i] - 0.25f * c0v - dxx[i];
    }
  }
}

// ============================ launcher ======================================
extern "C" void kernel_launch(void* const* d_in, const int* in_sizes, int n_in,
                              void* d_out, int out_size, void* d_ws, size_t ws_size,
                              hipStream_t stream) {
  const float* E_ent   = (const float*)d_in[0];
  const float* E_rel   = (const float*)d_in[1];
  const float* W       = (const float*)d_in[2];
  const float* b       = (const float*)d_in[3];
  const int*   samples = (const int*)d_in[4];
  float* out = (float*)d_out;
  float* ws  = (float*)d_ws;

  float* VA = ws;            // 65536 f32 (V0 -> final V)
  float* VB = ws + 65536;    // T scratch
  float* VC = ws + 131072;   // V1
  float* ub = ws + 196608;   // 256
  float* c0 = ws + 196864;   // 1

  gj_inv_kernel<<<1, 1024, 0, stream>>>(W, VA);
  // Newton-Schulz polish x2: V <- V(2I - (W-I)V)
  ns_mt_kernel<<<64, 64, 0, stream>>>(W, VA, VB);
  ns_upd_kernel<<<64, 64, 0, stream>>>(VA, VB, VC);
  ns_mt_kernel<<<64, 64, 0, stream>>>(W, VC, VB);
  ns_upd_kernel<<<64, 64, 0, stream>>>(VC, VB, VA);
  compute_u_kernel<<<1, 256, 0, stream>>>(VA, b, ub, c0);

  main_kernel<<<65536 / 32, 256, 0, stream>>>(E_ent, E_rel, samples, VA, ub, c0, out);
}